// Round 3
// baseline (612.266 us; speedup 1.0000x reference)
//
#include <hip/hip_runtime.h>
#include <hip/hip_bf16.h>
#include <stdint.h>

typedef __attribute__((ext_vector_type(8))) short short8;
typedef __attribute__((ext_vector_type(4))) float float4v;

__device__ __forceinline__ uint16_t f2bf(float f){
  union { float f; uint32_t i; } c; c.f = f;
  uint32_t r = c.i + 0x7fffu + ((c.i >> 16) & 1u);   // round-to-nearest-even
  return (uint16_t)(r >> 16);
}

// load 8 contiguous floats, convert to bf16 short8 (MFMA operand)
__device__ __forceinline__ short8 ld8f_bf(const float* p){
  float4v u = *(const float4v*)p;
  float4v v = *(const float4v*)(p + 4);
  short8 r;
  r[0] = (short)f2bf(u[0]); r[1] = (short)f2bf(u[1]);
  r[2] = (short)f2bf(u[2]); r[3] = (short)f2bf(u[3]);
  r[4] = (short)f2bf(v[0]); r[5] = (short)f2bf(v[1]);
  r[6] = (short)f2bf(v[2]); r[7] = (short)f2bf(v[3]);
  return r;
}

// ---- CSR build -------------------------------------------------------------

__global__ void hist_kernel(const int* __restrict__ ei, int E, int n,
                            int* __restrict__ deg){
  int e = blockIdx.x * 256 + threadIdx.x;
  if (e < E){
    unsigned d = (unsigned)ei[E + e];
    if (d >= (unsigned)n) d = 0;           // defensive clamp
    atomicAdd(&deg[d], 1);
  }
}

__global__ __launch_bounds__(1024) void scan_kernel(const int* __restrict__ deg, int n,
                                                    int* __restrict__ rowptr,
                                                    int* __restrict__ cursor){
  __shared__ int warp_tot[16];
  int tid = threadIdx.x, lane = tid & 63, wid = tid >> 6;
  int carry = 0;
  for (int base = 0; base < n; base += 1024){
    int i = base + tid;
    int dv = (i < n) ? deg[i] : 0;
    int v = dv;
    #pragma unroll
    for (int off = 1; off < 64; off <<= 1){
      int t = __shfl_up(v, off, 64);
      if (lane >= off) v += t;
    }
    if (lane == 63) warp_tot[wid] = v;
    __syncthreads();
    int wbase = 0, ctot = 0;
    #pragma unroll
    for (int w = 0; w < 16; ++w){
      int t = warp_tot[w];
      if (w < wid) wbase += t;
      ctot += t;
    }
    int excl = carry + wbase + (v - dv);   // exclusive prefix
    if (i < n){ rowptr[i] = excl; cursor[i] = excl; }
    carry += ctot;                          // identical in every thread
    __syncthreads();                        // protect warp_tot before next chunk
  }
  if (tid == 0) rowptr[n] = carry;
}

__global__ void scatter_kernel(const int* __restrict__ ei, int E, int n,
                               int* __restrict__ cursor, int* __restrict__ esrc){
  int e = blockIdx.x * 256 + threadIdx.x;
  if (e < E){
    unsigned s = (unsigned)ei[e];
    unsigned d = (unsigned)ei[E + e];
    if (s >= (unsigned)n) s = 0;           // defensive clamp
    if (d >= (unsigned)n) d = 0;
    unsigned p = (unsigned)atomicAdd(&cursor[d], 1);
    if (p < (unsigned)E) esrc[p] = (int)s; // defensive bound
  }
}

// ---- mean aggregation: one wave per node, lane holds 2 fp32 features -------
// input fp32 [n,128], output bf16 [n,128] (feeds MFMA directly)

__global__ __launch_bounds__(256) void agg_kernel(const float* __restrict__ xf,
                                                  const int* __restrict__ rowptr,
                                                  const int* __restrict__ esrc,
                                                  uint32_t* __restrict__ aggw, int n){
  int node = blockIdx.x * 4 + (threadIdx.x >> 6);
  if (node >= n) return;
  int lane = threadIdx.x & 63;
  const float2* xv = (const float2*)xf;
  int beg = rowptr[node], end = rowptr[node + 1];
  if (beg < 0) beg = 0;
  if (end > beg + n) end = beg;            // defensive: degenerate rowptr
  float ax = 0.f, ay = 0.f;
  for (int e = beg; e < end; ++e){
    unsigned sa = (unsigned)esrc[e];
    if (sa >= (unsigned)n) sa = 0;         // defensive clamp (kills wild reads)
    float2 w = xv[(size_t)sa * 64 + lane];
    ax += w.x; ay += w.y;
  }
  float inv = 1.f / fmaxf((float)(end - beg), 1.f);
  ax *= inv; ay *= inv;
  uint32_t lo = f2bf(ax), hi = f2bf(ay);
  aggw[(size_t)node * 64 + lane] = lo | (hi << 16);
}

// ---- fused SAGE linear: out = [relu]( agg@Wl^T + b + xin@Wr^T ) ------------
// MFMA 16x16x32 bf16. A-frag: A[m=lane&15][k=quad*8+j]; B-frag: B[k][n=lane&15];
// C/D: col=lane&15, row=quad*4+reg (HW-verified layouts).
// Aagg is bf16 [n,128]; Ax/W/bias/out are fp32. NOTE: no __restrict__ on
// Ax/out — the layer-3 launch runs IN PLACE (Ax region == out region); each
// wave reads only the rows it writes, stores happen after all loads.

__global__ __launch_bounds__(256) void gemm_kernel(
    const uint16_t* __restrict__ Aagg, const float* Ax,
    const float* __restrict__ Wl,   const float* __restrict__ Wr,
    const float* __restrict__ bias, float* out,
    int relu, int n){
  int lane = threadIdx.x & 63, wid = threadIdx.x >> 6;
  int m = lane & 15, quad = lane >> 4;
  int r0 = blockIdx.x * 64 + wid * 16;
  int arow = r0 + m; if (arow > n - 1) arow = n - 1;   // clamp tail reads
  float4v acc[8];
  #pragma unroll
  for (int ct = 0; ct < 8; ++ct) acc[ct] = (float4v){0.f, 0.f, 0.f, 0.f};

  #pragma unroll
  for (int ks = 0; ks < 4; ++ks){
    // part 0: Aagg (bf16) x Wl
    short8 a0 = *(const short8*)(Aagg + (size_t)arow * 128 + ks * 32 + quad * 8);
    // part 1: Ax (fp32->bf16) x Wr
    short8 a1 = ld8f_bf(Ax + (size_t)arow * 128 + ks * 32 + quad * 8);
    #pragma unroll
    for (int ct = 0; ct < 8; ++ct){
      // B[k][col] = W[col][k]; col = ct*16 + m
      short8 b0 = ld8f_bf(Wl + (size_t)(ct * 16 + m) * 128 + ks * 32 + quad * 8);
      acc[ct] = __builtin_amdgcn_mfma_f32_16x16x32_bf16(a0, b0, acc[ct], 0, 0, 0);
      short8 b1 = ld8f_bf(Wr + (size_t)(ct * 16 + m) * 128 + ks * 32 + quad * 8);
      acc[ct] = __builtin_amdgcn_mfma_f32_16x16x32_bf16(a1, b1, acc[ct], 0, 0, 0);
    }
  }

  #pragma unroll
  for (int ct = 0; ct < 8; ++ct){
    int col = ct * 16 + m;
    float bv = bias[col];
    #pragma unroll
    for (int i = 0; i < 4; ++i){
      int grow = r0 + quad * 4 + i;
      if (grow < n){
        float v = acc[ct][i] + bv;
        if (relu) v = fmaxf(v, 0.f);
        out[(size_t)grow * 128 + col] = v;
      }
    }
  }
}

// ---- launcher --------------------------------------------------------------

extern "C" void kernel_launch(void* const* d_in, const int* in_sizes, int n_in,
                              void* d_out, int out_size, void* d_ws, size_t ws_size,
                              hipStream_t stream) {
  const float* x   = (const float*)d_in[0];   // fp32 [N,128]
  const int*   ei  = (const int*)d_in[1];     // int32 [2,E]
  const float* W1l = (const float*)d_in[2];
  const float* b1l = (const float*)d_in[3];
  const float* W1r = (const float*)d_in[4];
  const float* W2l = (const float*)d_in[5];
  const float* b2l = (const float*)d_in[6];
  const float* W2r = (const float*)d_in[7];
  const float* W3l = (const float*)d_in[8];
  const float* b3l = (const float*)d_in[9];
  const float* W3r = (const float*)d_in[10];
  float* out = (float*)d_out;

  const int n = in_sizes[0] / 128;
  const int E = in_sizes[1] / 2;
  const size_t half = (size_t)n * 128;        // elements per output half

  size_t off = 0;
  auto carve = [&](size_t bytes) -> void* {
    void* p = (char*)d_ws + off;
    off += (bytes + 255) & ~(size_t)255;
    return p;
  };
  int*      deg    = (int*)carve((size_t)n * 4);
  int*      rowptr = (int*)carve((size_t)(n + 1) * 4);
  int*      cursor = (int*)carve((size_t)n * 4);
  int*      esrc   = (int*)carve((size_t)E * 4);
  uint16_t* agg    = (uint16_t*)carve(half * 2);           // bf16 [n,128]

  // x1 (fp32) in ws if it fits, else in out's second half (layer-3 in place)
  float* x1;
  size_t x1_bytes = (half * 4 + 255) & ~(size_t)255;
  if (ws_size >= off + x1_bytes) x1 = (float*)carve(half * 4);
  else                           x1 = out + half;

  hipMemsetAsync(deg, 0, (size_t)n * 4, stream);
  hipMemsetAsync(esrc, 0, (size_t)E * 4, stream);  // unwritten slot -> node 0

  int eblk = (E + 255) / 256;
  hist_kernel<<<eblk, 256, 0, stream>>>(ei, E, n, deg);
  scan_kernel<<<1, 1024, 0, stream>>>(deg, n, rowptr, cursor);
  scatter_kernel<<<eblk, 256, 0, stream>>>(ei, E, n, cursor, esrc);

  int ablk = (n + 3) / 4;
  int gblk = (n + 63) / 64;

  // layer 1: x1 = relu(agg@W1l^T + b1l + x@W1r^T)
  agg_kernel<<<ablk, 256, 0, stream>>>(x, rowptr, esrc, (uint32_t*)agg, n);
  gemm_kernel<<<gblk, 256, 0, stream>>>(agg, x, W1l, W1r, b1l, x1, 1, n);

  // shared aggregation of x1 for layers 2 and 3 (agg buffer reused)
  agg_kernel<<<ablk, 256, 0, stream>>>(x1, rowptr, esrc, (uint32_t*)agg, n);

  // layer 2 -> h_ (first half); layer 3 -> h (second half, possibly in place)
  gemm_kernel<<<gblk, 256, 0, stream>>>(agg, x1, W2l, W2r, b2l, out, 0, n);
  gemm_kernel<<<gblk, 256, 0, stream>>>(agg, x1, W3l, W3r, b3l, out + half, 0, n);
}

// Round 4
// 394.969 us; speedup vs baseline: 1.5502x; 1.5502x over previous
//
#include <hip/hip_runtime.h>
#include <stdint.h>

typedef __attribute__((ext_vector_type(8))) short short8;
typedef __attribute__((ext_vector_type(4))) float float4v;

__device__ __forceinline__ uint16_t f2bf(float f){
  union { float f; uint32_t i; } c; c.f = f;
  uint32_t r = c.i + 0x7fffu + ((c.i >> 16) & 1u);   // round-to-nearest-even
  return (uint16_t)(r >> 16);
}
__device__ __forceinline__ void acc_bf2(uint32_t w, float& x, float& y){
  union { uint32_t i; float f; } a, b;
  a.i = w << 16; b.i = w & 0xffff0000u;
  x += a.f; y += b.f;
}
// load 8 contiguous floats, convert to bf16 short8 (fallback A-operand path)
__device__ __forceinline__ short8 ld8f_bf(const float* p){
  float4v u = *(const float4v*)p;
  float4v v = *(const float4v*)(p + 4);
  short8 r;
  r[0] = (short)f2bf(u[0]); r[1] = (short)f2bf(u[1]);
  r[2] = (short)f2bf(u[2]); r[3] = (short)f2bf(u[3]);
  r[4] = (short)f2bf(v[0]); r[5] = (short)f2bf(v[1]);
  r[6] = (short)f2bf(v[2]); r[7] = (short)f2bf(v[3]);
  return r;
}

// ---- one-shot fp32 -> bf16 conversion of x and the 6 weight matrices -------

__global__ void conv_kernel(const float* __restrict__ x,
                            const float* __restrict__ w0, const float* __restrict__ w1,
                            const float* __restrict__ w2, const float* __restrict__ w3,
                            const float* __restrict__ w4, const float* __restrict__ w5,
                            uint16_t* __restrict__ xb, uint16_t* __restrict__ wb, int nx){
  int i = blockIdx.x * 256 + threadIdx.x;
  int stride = gridDim.x * 256;
  for (int j = i; j < nx; j += stride) xb[j] = f2bf(x[j]);
  const int WSZ = 128 * 128;
  for (int j = i; j < 6 * WSZ; j += stride){
    int t = j >> 14, o = j & (WSZ - 1);
    const float* w = t == 0 ? w0 : t == 1 ? w1 : t == 2 ? w2 : t == 3 ? w3 : t == 4 ? w4 : w5;
    wb[j] = f2bf(w[o]);
  }
}

// ---- CSR build -------------------------------------------------------------

__global__ void hist_kernel(const int* __restrict__ ei, int E,
                            int* __restrict__ deg){
  int e = blockIdx.x * 256 + threadIdx.x;
  if (e < E) atomicAdd(&deg[ei[E + e]], 1);
}

__global__ __launch_bounds__(1024) void scan_kernel(const int* __restrict__ deg, int n,
                                                    int* __restrict__ rowptr,
                                                    int* __restrict__ cursor){
  __shared__ int warp_tot[16];
  int tid = threadIdx.x, lane = tid & 63, wid = tid >> 6;
  int carry = 0;
  for (int base = 0; base < n; base += 4096){
    int i0 = base + tid * 4;
    int d0 = 0, d1 = 0, d2 = 0, d3 = 0;
    if (i0 + 3 < n){
      int4 d4 = *(const int4*)(deg + i0);
      d0 = d4.x; d1 = d4.y; d2 = d4.z; d3 = d4.w;
    } else {
      if (i0     < n) d0 = deg[i0];
      if (i0 + 1 < n) d1 = deg[i0 + 1];
      if (i0 + 2 < n) d2 = deg[i0 + 2];
      if (i0 + 3 < n) d3 = deg[i0 + 3];
    }
    int tot = d0 + d1 + d2 + d3;
    int v = tot;
    #pragma unroll
    for (int off = 1; off < 64; off <<= 1){
      int t = __shfl_up(v, off, 64);
      if (lane >= off) v += t;
    }
    if (lane == 63) warp_tot[wid] = v;
    __syncthreads();
    int wbase = 0, ctot = 0;
    #pragma unroll
    for (int w = 0; w < 16; ++w){
      int t = warp_tot[w];
      if (w < wid) wbase += t;
      ctot += t;
    }
    int excl = carry + wbase + (v - tot);   // exclusive prefix of this thread's 4
    if (i0 + 3 < n){
      int4 r; r.x = excl; r.y = excl + d0; r.z = excl + d0 + d1; r.w = excl + d0 + d1 + d2;
      *(int4*)(rowptr + i0) = r;
      *(int4*)(cursor + i0) = r;
    } else {
      int p = excl;
      if (i0     < n){ rowptr[i0]     = p; cursor[i0]     = p; p += d0; }
      if (i0 + 1 < n){ rowptr[i0 + 1] = p; cursor[i0 + 1] = p; p += d1; }
      if (i0 + 2 < n){ rowptr[i0 + 2] = p; cursor[i0 + 2] = p; p += d2; }
      if (i0 + 3 < n){ rowptr[i0 + 3] = p; cursor[i0 + 3] = p; }
    }
    carry += ctot;
    __syncthreads();
  }
  if (tid == 0) rowptr[n] = carry;
}

__global__ void scatter_kernel(const int* __restrict__ ei, int E,
                               int* __restrict__ cursor, int* __restrict__ esrc){
  int e = blockIdx.x * 256 + threadIdx.x;
  if (e < E){
    int s = ei[e], d = ei[E + e];
    int p = atomicAdd(&cursor[d], 1);
    esrc[p] = s;
  }
}

// ---- mean aggregation: one wave per node, lane holds 2 features ------------
// BF=true: input bf16 [n,128] (uint32 pairs); BF=false: fp32 [n,128].
// Output bf16 [n,128]. 4-deep unroll -> 4 independent row gathers in flight.

template<bool BF>
__global__ __launch_bounds__(256) void agg_kernel(const void* __restrict__ xin,
                                                  const int* __restrict__ rowptr,
                                                  const int* __restrict__ esrc,
                                                  uint32_t* __restrict__ aggw, int n){
  int node = blockIdx.x * 4 + (threadIdx.x >> 6);
  if (node >= n) return;
  int lane = threadIdx.x & 63;
  const uint32_t* xb = (const uint32_t*)xin;
  const float2*   xf = (const float2*)xin;
  int beg = rowptr[node], end = rowptr[node + 1];
  float ax = 0.f, ay = 0.f;
  int e = beg;
  for (; e + 3 < end; e += 4){
    int s0 = esrc[e], s1 = esrc[e + 1], s2 = esrc[e + 2], s3 = esrc[e + 3];
    if (BF){
      uint32_t w0 = xb[(size_t)s0 * 64 + lane];
      uint32_t w1 = xb[(size_t)s1 * 64 + lane];
      uint32_t w2 = xb[(size_t)s2 * 64 + lane];
      uint32_t w3 = xb[(size_t)s3 * 64 + lane];
      acc_bf2(w0, ax, ay); acc_bf2(w1, ax, ay);
      acc_bf2(w2, ax, ay); acc_bf2(w3, ax, ay);
    } else {
      float2 w0 = xf[(size_t)s0 * 64 + lane];
      float2 w1 = xf[(size_t)s1 * 64 + lane];
      float2 w2 = xf[(size_t)s2 * 64 + lane];
      float2 w3 = xf[(size_t)s3 * 64 + lane];
      ax += w0.x + w1.x + w2.x + w3.x;
      ay += w0.y + w1.y + w2.y + w3.y;
    }
  }
  for (; e < end; ++e){
    int s = esrc[e];
    if (BF){ acc_bf2(xb[(size_t)s * 64 + lane], ax, ay); }
    else   { float2 w = xf[(size_t)s * 64 + lane]; ax += w.x; ay += w.y; }
  }
  float inv = 1.f / fmaxf((float)(end - beg), 1.f);
  ax *= inv; ay *= inv;
  uint32_t lo = f2bf(ax), hi = f2bf(ay);
  aggw[(size_t)node * 64 + lane] = lo | (hi << 16);
}

// ---- fused SAGE linear: out = [relu]( agg@Wl^T + b + xin@Wr^T ) ------------
// MFMA 16x16x32 bf16. A-frag: A[m=lane&15][k=quad*8+j]; B-frag: B[k][n=lane&15];
// C/D: col=lane&15, row=quad*4+reg (HW-verified layouts).
// AXBF: Ax is bf16 (else fp32, converted per load — only 32 f2bf/lane).
// OUTBF: store bf16 (internal x1) else fp32 (final outputs).
// No __restrict__ on Ax/outp: fallback layer-3 runs in place (per-wave
// read-set == write-set; loads precede stores in program order).

template<bool AXBF, bool OUTBF>
__global__ __launch_bounds__(256) void gemm_kernel(
    const uint16_t* __restrict__ Aagg, const void* Ax,
    const uint16_t* __restrict__ Wl, const uint16_t* __restrict__ Wr,
    const float* __restrict__ bias, void* outp, int relu, int n){
  int lane = threadIdx.x & 63, wid = threadIdx.x >> 6;
  int m = lane & 15, quad = lane >> 4;
  int r0 = blockIdx.x * 64 + wid * 16;
  int arow = r0 + m; if (arow > n - 1) arow = n - 1;   // clamp tail reads
  float4v acc[8];
  #pragma unroll
  for (int ct = 0; ct < 8; ++ct) acc[ct] = (float4v){0.f, 0.f, 0.f, 0.f};

  #pragma unroll
  for (int ks = 0; ks < 4; ++ks){
    short8 a0 = *(const short8*)(Aagg + (size_t)arow * 128 + ks * 32 + quad * 8);
    short8 a1;
    if (AXBF) a1 = *(const short8*)((const uint16_t*)Ax + (size_t)arow * 128 + ks * 32 + quad * 8);
    else      a1 = ld8f_bf((const float*)Ax + (size_t)arow * 128 + ks * 32 + quad * 8);
    #pragma unroll
    for (int ct = 0; ct < 8; ++ct){
      // B[k][col] = W[col][k]; col = ct*16 + m
      short8 b0 = *(const short8*)(Wl + (size_t)(ct * 16 + m) * 128 + ks * 32 + quad * 8);
      acc[ct] = __builtin_amdgcn_mfma_f32_16x16x32_bf16(a0, b0, acc[ct], 0, 0, 0);
      short8 b1 = *(const short8*)(Wr + (size_t)(ct * 16 + m) * 128 + ks * 32 + quad * 8);
      acc[ct] = __builtin_amdgcn_mfma_f32_16x16x32_bf16(a1, b1, acc[ct], 0, 0, 0);
    }
  }

  #pragma unroll
  for (int ct = 0; ct < 8; ++ct){
    int col = ct * 16 + m;
    float bv = bias[col];
    #pragma unroll
    for (int i = 0; i < 4; ++i){
      int grow = r0 + quad * 4 + i;
      if (grow < n){
        float v = acc[ct][i] + bv;
        if (relu) v = fmaxf(v, 0.f);
        if (OUTBF) ((uint16_t*)outp)[(size_t)grow * 128 + col] = f2bf(v);
        else       ((float*)outp)[(size_t)grow * 128 + col] = v;
      }
    }
  }
}

// ---- launcher --------------------------------------------------------------

extern "C" void kernel_launch(void* const* d_in, const int* in_sizes, int n_in,
                              void* d_out, int out_size, void* d_ws, size_t ws_size,
                              hipStream_t stream) {
  const float* x   = (const float*)d_in[0];   // fp32 [N,128]
  const int*   ei  = (const int*)d_in[1];     // int32 [2,E]
  const float* W1l = (const float*)d_in[2];
  const float* b1l = (const float*)d_in[3];
  const float* W1r = (const float*)d_in[4];
  const float* W2l = (const float*)d_in[5];
  const float* b2l = (const float*)d_in[6];
  const float* W2r = (const float*)d_in[7];
  const float* W3l = (const float*)d_in[8];
  const float* b3l = (const float*)d_in[9];
  const float* W3r = (const float*)d_in[10];
  float* out = (float*)d_out;

  const int n = in_sizes[0] / 128;
  const int E = in_sizes[1] / 2;
  const size_t half = (size_t)n * 128;        // elements per output half
  const int WSZ = 128 * 128;

  size_t off = 0;
  auto carve = [&](size_t bytes) -> void* {
    void* p = (char*)d_ws + off;
    off += (bytes + 255) & ~(size_t)255;
    return p;
  };
  int*      deg    = (int*)carve((size_t)n * 4);
  int*      rowptr = (int*)carve((size_t)(n + 1) * 4);
  int*      cursor = (int*)carve((size_t)n * 4);
  int*      esrc   = (int*)carve((size_t)E * 4);
  uint16_t* agg    = (uint16_t*)carve(half * 2);        // bf16 [n,128]
  uint16_t* xb     = (uint16_t*)carve(half * 2);        // bf16 copy of x
  uint16_t* wb     = (uint16_t*)carve((size_t)6 * WSZ * 2); // bf16 weights

  // x1: bf16 in ws if it fits (fast path), else fp32 in out's second half
  uint16_t* x1b = nullptr;
  float*    x1f = nullptr;
  size_t x1_bytes = (half * 2 + 255) & ~(size_t)255;
  if (ws_size >= off + x1_bytes) x1b = (uint16_t*)carve(half * 2);
  else                           x1f = out + half;

  hipMemsetAsync(deg, 0, (size_t)n * 4, stream);

  int eblk = (E + 255) / 256;
  int cblk = ((int)half + 255) / 256;
  conv_kernel<<<cblk, 256, 0, stream>>>(x, W1l, W1r, W2l, W2r, W3l, W3r,
                                        xb, wb, (int)half);
  hist_kernel<<<eblk, 256, 0, stream>>>(ei, E, deg);
  scan_kernel<<<1, 1024, 0, stream>>>(deg, n, rowptr, cursor);
  scatter_kernel<<<eblk, 256, 0, stream>>>(ei, E, cursor, esrc);

  int ablk = (n + 3) / 4;
  int gblk = (n + 63) / 64;
  const uint16_t *Wb1l = wb, *Wb1r = wb + WSZ, *Wb2l = wb + 2 * WSZ,
                 *Wb2r = wb + 3 * WSZ, *Wb3l = wb + 4 * WSZ, *Wb3r = wb + 5 * WSZ;

  // layer 1 aggregation over bf16 x
  agg_kernel<true><<<ablk, 256, 0, stream>>>(xb, rowptr, esrc, (uint32_t*)agg, n);

  if (x1b){
    // fast path: x1 kept bf16 in ws
    gemm_kernel<true, true><<<gblk, 256, 0, stream>>>(agg, xb, Wb1l, Wb1r, b1l, x1b, 1, n);
    agg_kernel<true><<<ablk, 256, 0, stream>>>(x1b, rowptr, esrc, (uint32_t*)agg, n);
    gemm_kernel<true, false><<<gblk, 256, 0, stream>>>(agg, x1b, Wb2l, Wb2r, b2l, out, 0, n);
    gemm_kernel<true, false><<<gblk, 256, 0, stream>>>(agg, x1b, Wb3l, Wb3r, b3l, out + half, 0, n);
  } else {
    // fallback: x1 fp32 in out's second half; layer 3 runs in place
    gemm_kernel<true, false><<<gblk, 256, 0, stream>>>(agg, xb, Wb1l, Wb1r, b1l, x1f, 1, n);
    agg_kernel<false><<<ablk, 256, 0, stream>>>(x1f, rowptr, esrc, (uint32_t*)agg, n);
    gemm_kernel<false, false><<<gblk, 256, 0, stream>>>(agg, x1f, Wb2l, Wb2r, b2l, out, 0, n);
    gemm_kernel<false, false><<<gblk, 256, 0, stream>>>(agg, x1f, Wb3l, Wb3r, b3l, out + half, 0, n);
  }
}

// Round 5
// 304.925 us; speedup vs baseline: 2.0079x; 1.2953x over previous
//
#include <hip/hip_runtime.h>
#include <stdint.h>
#include <math.h>

typedef __attribute__((ext_vector_type(8))) short short8;
typedef __attribute__((ext_vector_type(4))) float float4v;

__device__ __forceinline__ uint16_t f2bf(float f){
  union { float f; uint32_t i; } c; c.f = f;
  uint32_t r = c.i + 0x7fffu + ((c.i >> 16) & 1u);   // round-to-nearest-even
  return (uint16_t)(r >> 16);
}
__device__ __forceinline__ uint32_t pack2(float lo, float hi){
  return (uint32_t)f2bf(lo) | ((uint32_t)f2bf(hi) << 16);
}
__device__ __forceinline__ void acc_bf2(uint32_t w, float& x, float& y){
  union { uint32_t i; float f; } a, b;
  a.i = w << 16; b.i = w & 0xffff0000u;
  x += a.f; y += b.f;
}
__device__ __forceinline__ void accum8(uint4 v, float* a){
  acc_bf2(v.x, a[0], a[1]); acc_bf2(v.y, a[2], a[3]);
  acc_bf2(v.z, a[4], a[5]); acc_bf2(v.w, a[6], a[7]);
}
// load 8 contiguous floats, convert to bf16 short8 (fallback A-operand path)
__device__ __forceinline__ short8 ld8f_bf(const float* p){
  float4v u = *(const float4v*)p;
  float4v v = *(const float4v*)(p + 4);
  short8 r;
  r[0] = (short)f2bf(u[0]); r[1] = (short)f2bf(u[1]);
  r[2] = (short)f2bf(u[2]); r[3] = (short)f2bf(u[3]);
  r[4] = (short)f2bf(v[0]); r[5] = (short)f2bf(v[1]);
  r[6] = (short)f2bf(v[2]); r[7] = (short)f2bf(v[3]);
  return r;
}

// ---- one-shot fp32 -> bf16 conversion of x and the 6 weight matrices -------

__global__ void conv_kernel(const float* __restrict__ x,
                            const float* __restrict__ w0, const float* __restrict__ w1,
                            const float* __restrict__ w2, const float* __restrict__ w3,
                            const float* __restrict__ w4, const float* __restrict__ w5,
                            uint16_t* __restrict__ xb, uint16_t* __restrict__ wb, int nx){
  int i = blockIdx.x * 256 + threadIdx.x;
  int stride = gridDim.x * 256;
  for (int j = i; j < nx; j += stride) xb[j] = f2bf(x[j]);
  const int WSZ = 128 * 128;
  for (int j = i; j < 6 * WSZ; j += stride){
    int t = j >> 14, o = j & (WSZ - 1);
    const float* w = t == 0 ? w0 : t == 1 ? w1 : t == 2 ? w2 : t == 3 ? w3 : t == 4 ? w4 : w5;
    wb[j] = f2bf(w[o]);
  }
}

// ---- CSR build, two-level counting sort ------------------------------------
// Bucket = dst >> 8 (256 nodes per bucket, NB <= 256 buckets since n <= 65536).
// Pass 1: bin edges bucket-major with per-block LDS hist + chunked reservation
// (writes are contiguous per (block,bucket) chunk -> full-line writebacks).
// Pass 2: one WG per bucket: LDS hist over 256 local nodes, LDS scan, emit
// per-node (beg,end) + scatter esrc within the bucket's private region
// (single WG = single XCD = L2 assembles full lines before eviction).

#define P1_EPT 8   // edges per thread, 512 threads -> 4096-edge tiles

__global__ __launch_bounds__(512) void bin_kernel(const int* __restrict__ ei, int E,
                                                  int NB, int CAP,
                                                  int* __restrict__ fill,
                                                  int2* __restrict__ bins){
  __shared__ int hist[256], base[256], cur[256];
  int tid = threadIdx.x;
  if (tid < 256){ hist[tid] = 0; cur[tid] = 0; }
  __syncthreads();
  int src[P1_EPT], dst[P1_EPT];
  int e0 = blockIdx.x * (512 * P1_EPT);
  #pragma unroll
  for (int k = 0; k < P1_EPT; ++k){
    int e = e0 + k * 512 + tid;
    bool ok = e < E;
    src[k] = ok ? ei[e] : 0;
    dst[k] = ok ? ei[E + e] : -1;          // sentinel
    if (ok) atomicAdd(&hist[dst[k] >> 8], 1);
  }
  __syncthreads();
  if (tid < NB && hist[tid] > 0) base[tid] = atomicAdd(&fill[tid], hist[tid]);
  __syncthreads();
  #pragma unroll
  for (int k = 0; k < P1_EPT; ++k){
    if (dst[k] >= 0){
      int b = dst[k] >> 8;
      int loc = base[b] + atomicAdd(&cur[b], 1);
      if (loc < CAP) bins[(size_t)b * CAP + loc] = make_int2(src[k], dst[k]);
    }
  }
}

__global__ __launch_bounds__(512) void build_kernel(const int2* __restrict__ bins,
                                                    const int* __restrict__ fill,
                                                    int CAP, int n,
                                                    int2* __restrict__ rowptr2,
                                                    int* __restrict__ esrc){
  __shared__ int h[256], s[256], cursor[256];
  int b = blockIdx.x, tid = threadIdx.x;
  int cnt = fill[b]; if (cnt > CAP) cnt = CAP;
  int gbase = b * CAP;
  if (tid < 256) h[tid] = 0;
  __syncthreads();
  for (int i = tid; i < cnt; i += 512)
    atomicAdd(&h[bins[(size_t)gbase + i].y & 255], 1);
  __syncthreads();
  if (tid < 256) s[tid] = h[tid];
  __syncthreads();
  #pragma unroll
  for (int off = 1; off < 256; off <<= 1){
    int v = 0;
    if (tid < 256 && tid >= off) v = s[tid - off];
    __syncthreads();
    if (tid < 256) s[tid] += v;
    __syncthreads();
  }
  if (tid < 256){
    int node = (b << 8) + tid;
    int excl = s[tid] - h[tid];
    if (node < n) rowptr2[node] = make_int2(gbase + excl, gbase + s[tid]);
    cursor[tid] = gbase + excl;
  }
  __syncthreads();
  for (int i = tid; i < cnt; i += 512){
    int2 e = bins[(size_t)gbase + i];
    int p = atomicAdd(&cursor[e.y & 255], 1);
    esrc[p] = e.x;
  }
}

// ---- mean aggregation ------------------------------------------------------
// BF=true: input bf16 rows (256B), 16B/lane, 4 edges per wave.
// BF=false: input fp32 rows (512B), 16B/lane, 2 edges per wave.
// Output bf16 [n,128]. 2-deep unroll -> up to 8 row-gathers in flight/wave.

template<bool BF>
__global__ __launch_bounds__(256) void agg_kernel(const void* __restrict__ xin,
                                                  const int2* __restrict__ rowptr2,
                                                  const int* __restrict__ esrc,
                                                  uint16_t* __restrict__ aggw, int n){
  int node = blockIdx.x * 4 + (threadIdx.x >> 6);
  if (node >= n) return;
  int lane = threadIdx.x & 63;
  int2 be = rowptr2[node];
  int beg = be.x, end = be.y;
  float inv = 1.f / fmaxf((float)(end - beg), 1.f);
  if (BF){
    int sub = lane >> 4, fq = lane & 15;
    const uint4* xb = (const uint4*)xin;            // row = 16 x uint4
    float a[8] = {0.f,0.f,0.f,0.f,0.f,0.f,0.f,0.f};
    int e = beg + sub;
    for (; e + 4 < end; e += 8){
      int s0 = esrc[e], s1 = esrc[e + 4];
      uint4 v0 = xb[(size_t)s0 * 16 + fq];
      uint4 v1 = xb[(size_t)s1 * 16 + fq];
      accum8(v0, a); accum8(v1, a);
    }
    for (; e < end; e += 4){
      uint4 v0 = xb[(size_t)esrc[e] * 16 + fq];
      accum8(v0, a);
    }
    #pragma unroll
    for (int i = 0; i < 8; ++i){
      a[i] += __shfl_xor(a[i], 16);
      a[i] += __shfl_xor(a[i], 32);
      a[i] *= inv;
    }
    if (sub == 0){
      uint4 o;
      o.x = pack2(a[0], a[1]); o.y = pack2(a[2], a[3]);
      o.z = pack2(a[4], a[5]); o.w = pack2(a[6], a[7]);
      ((uint4*)aggw)[(size_t)node * 16 + fq] = o;
    }
  } else {
    int sub = lane >> 5, fq = lane & 31;
    const float4* xf = (const float4*)xin;          // row = 32 x float4
    float a0 = 0.f, a1 = 0.f, a2 = 0.f, a3 = 0.f;
    int e = beg + sub;
    for (; e + 2 < end; e += 4){
      int s0 = esrc[e], s1 = esrc[e + 2];
      float4 v0 = xf[(size_t)s0 * 32 + fq];
      float4 v1 = xf[(size_t)s1 * 32 + fq];
      a0 += v0.x + v1.x; a1 += v0.y + v1.y;
      a2 += v0.z + v1.z; a3 += v0.w + v1.w;
    }
    for (; e < end; e += 2){
      float4 v0 = xf[(size_t)esrc[e] * 32 + fq];
      a0 += v0.x; a1 += v0.y; a2 += v0.z; a3 += v0.w;
    }
    a0 += __shfl_xor(a0, 32); a1 += __shfl_xor(a1, 32);
    a2 += __shfl_xor(a2, 32); a3 += __shfl_xor(a3, 32);
    a0 *= inv; a1 *= inv; a2 *= inv; a3 *= inv;
    if (sub == 0){
      uint2 o; o.x = pack2(a0, a1); o.y = pack2(a2, a3);
      ((uint2*)aggw)[(size_t)node * 32 + fq] = o;
    }
  }
}

// ---- fused SAGE linear: out = [relu]( agg@Wl^T + b + xin@Wr^T ) ------------
// MFMA 16x16x32 bf16. A-frag: A[m=lane&15][k=quad*8+j]; B-frag: B[k][n=lane&15];
// C/D: col=lane&15, row=quad*4+reg (HW-verified layouts).
// AXBF: Ax is bf16 (else fp32, converted per load). OUTBF: store bf16 (x1)
// else fp32 (final outputs). No __restrict__ on Ax/outp: fallback layer-3
// runs in place (per-wave read-set == write-set; loads precede stores).

template<bool AXBF, bool OUTBF>
__global__ __launch_bounds__(256) void gemm_kernel(
    const uint16_t* __restrict__ Aagg, const void* Ax,
    const uint16_t* __restrict__ Wl, const uint16_t* __restrict__ Wr,
    const float* __restrict__ bias, void* outp, int relu, int n){
  int lane = threadIdx.x & 63, wid = threadIdx.x >> 6;
  int m = lane & 15, quad = lane >> 4;
  int r0 = blockIdx.x * 64 + wid * 16;
  int arow = r0 + m; if (arow > n - 1) arow = n - 1;   // clamp tail reads
  float4v acc[8];
  #pragma unroll
  for (int ct = 0; ct < 8; ++ct) acc[ct] = (float4v){0.f, 0.f, 0.f, 0.f};

  #pragma unroll
  for (int ks = 0; ks < 4; ++ks){
    short8 a0 = *(const short8*)(Aagg + (size_t)arow * 128 + ks * 32 + quad * 8);
    short8 a1;
    if (AXBF) a1 = *(const short8*)((const uint16_t*)Ax + (size_t)arow * 128 + ks * 32 + quad * 8);
    else      a1 = ld8f_bf((const float*)Ax + (size_t)arow * 128 + ks * 32 + quad * 8);
    #pragma unroll
    for (int ct = 0; ct < 8; ++ct){
      // B[k][col] = W[col][k]; col = ct*16 + m
      short8 b0 = *(const short8*)(Wl + (size_t)(ct * 16 + m) * 128 + ks * 32 + quad * 8);
      acc[ct] = __builtin_amdgcn_mfma_f32_16x16x32_bf16(a0, b0, acc[ct], 0, 0, 0);
      short8 b1 = *(const short8*)(Wr + (size_t)(ct * 16 + m) * 128 + ks * 32 + quad * 8);
      acc[ct] = __builtin_amdgcn_mfma_f32_16x16x32_bf16(a1, b1, acc[ct], 0, 0, 0);
    }
  }

  #pragma unroll
  for (int ct = 0; ct < 8; ++ct){
    int col = ct * 16 + m;
    float bv = bias[col];
    #pragma unroll
    for (int i = 0; i < 4; ++i){
      int grow = r0 + quad * 4 + i;
      if (grow < n){
        float v = acc[ct][i] + bv;
        if (relu) v = fmaxf(v, 0.f);
        if (OUTBF) ((uint16_t*)outp)[(size_t)grow * 128 + col] = f2bf(v);
        else       ((float*)outp)[(size_t)grow * 128 + col] = v;
      }
    }
  }
}

// ---- launcher --------------------------------------------------------------

extern "C" void kernel_launch(void* const* d_in, const int* in_sizes, int n_in,
                              void* d_out, int out_size, void* d_ws, size_t ws_size,
                              hipStream_t stream) {
  const float* x   = (const float*)d_in[0];   // fp32 [N,128]
  const int*   ei  = (const int*)d_in[1];     // int32 [2,E]
  const float* W1l = (const float*)d_in[2];
  const float* b1l = (const float*)d_in[3];
  const float* W1r = (const float*)d_in[4];
  const float* W2l = (const float*)d_in[5];
  const float* b2l = (const float*)d_in[6];
  const float* W2r = (const float*)d_in[7];
  const float* W3l = (const float*)d_in[8];
  const float* b3l = (const float*)d_in[9];
  const float* W3r = (const float*)d_in[10];
  float* out = (float*)d_out;

  const int n = in_sizes[0] / 128;
  const int E = in_sizes[1] / 2;
  const size_t half = (size_t)n * 128;        // elements per output half
  const int WSZ = 128 * 128;

  const int NB = (n + 255) >> 8;              // buckets of 256 nodes (n <= 65536)
  int mean = (E + NB - 1) / NB;
  int CAP = mean + 8 * (int)sqrt((double)mean) + 64;
  CAP = (CAP + 63) & ~63;                     // per-bucket capacity w/ 8-sigma slack

  size_t off = 0;
  auto carve = [&](size_t bytes) -> void* {
    void* p = (char*)d_ws + off;
    off += (bytes + 255) & ~(size_t)255;
    return p;
  };
  int2*     rowptr2 = (int2*)carve((size_t)n * 8);
  int*      fill    = (int*)carve((size_t)NB * 4);
  int*      esrc    = (int*)carve((size_t)NB * CAP * 4);
  uint16_t* xb      = (uint16_t*)carve(half * 2);            // bf16 copy of x
  uint16_t* wb      = (uint16_t*)carve((size_t)6 * WSZ * 2); // bf16 weights
  // bins (pass-1 staging) is dead before agg is first written: share a region
  size_t bins_b = (size_t)NB * CAP * 8, agg_b = half * 2;
  void* un = carve(bins_b > agg_b ? bins_b : agg_b);
  int2*     bins = (int2*)un;
  uint16_t* agg  = (uint16_t*)un;

  // x1: bf16 in ws if it fits (fast path), else fp32 in out's second half
  uint16_t* x1b = nullptr;
  float*    x1f = nullptr;
  size_t x1_bytes = (half * 2 + 255) & ~(size_t)255;
  if (ws_size >= off + x1_bytes) x1b = (uint16_t*)carve(half * 2);
  else                           x1f = out + half;

  hipMemsetAsync(fill, 0, (size_t)NB * 4, stream);

  int cblk = ((int)half + 255) / 256;
  conv_kernel<<<cblk, 256, 0, stream>>>(x, W1l, W1r, W2l, W2r, W3l, W3r,
                                        xb, wb, (int)half);
  int p1blk = (E + 512 * P1_EPT - 1) / (512 * P1_EPT);
  bin_kernel<<<p1blk, 512, 0, stream>>>(ei, E, NB, CAP, fill, bins);
  build_kernel<<<NB, 512, 0, stream>>>(bins, fill, CAP, n, rowptr2, esrc);

  int ablk = (n + 3) / 4;
  int gblk = (n + 63) / 64;
  const uint16_t *Wb1l = wb, *Wb1r = wb + WSZ, *Wb2l = wb + 2 * WSZ,
                 *Wb2r = wb + 3 * WSZ, *Wb3l = wb + 4 * WSZ, *Wb3r = wb + 5 * WSZ;

  // layer 1 aggregation over bf16 x (agg overlays bins — bins dead now)
  agg_kernel<true><<<ablk, 256, 0, stream>>>(xb, rowptr2, esrc, agg, n);

  if (x1b){
    // fast path: x1 kept bf16 in ws
    gemm_kernel<true, true><<<gblk, 256, 0, stream>>>(agg, xb, Wb1l, Wb1r, b1l, x1b, 1, n);
    agg_kernel<true><<<ablk, 256, 0, stream>>>(x1b, rowptr2, esrc, agg, n);
    gemm_kernel<true, false><<<gblk, 256, 0, stream>>>(agg, x1b, Wb2l, Wb2r, b2l, out, 0, n);
    gemm_kernel<true, false><<<gblk, 256, 0, stream>>>(agg, x1b, Wb3l, Wb3r, b3l, out + half, 0, n);
  } else {
    // fallback: x1 fp32 in out's second half; layer 3 runs in place
    gemm_kernel<true, false><<<gblk, 256, 0, stream>>>(agg, xb, Wb1l, Wb1r, b1l, x1f, 1, n);
    agg_kernel<false><<<ablk, 256, 0, stream>>>(x1f, rowptr2, esrc, agg, n);
    gemm_kernel<false, false><<<gblk, 256, 0, stream>>>(agg, x1f, Wb2l, Wb2r, b2l, out, 0, n);
    gemm_kernel<false, false><<<gblk, 256, 0, stream>>>(agg, x1f, Wb3l, Wb3r, b3l, out + half, 0, n);
  }
}